// Round 5
// baseline (651.422 us; speedup 1.0000x reference)
//
#include <hip/hip_runtime.h>

typedef _Float16 half8 __attribute__((ext_vector_type(8)));
typedef float floatx4 __attribute__((ext_vector_type(4)));

#define T_STEPS 256
#define BB      16
#define NTH     512
#define RING_W  16

// d_ws layout: weight frags (halves), then ring (64 groups x 16 slots x 4 KB), then flags
#define WHH0_H  0
#define WIH1_H  65536
#define WHH1_H  131072
#define WIH0_H  196608
#define RING_H  212992              // half index; byte 425984
#define FLAG_B  4620288             // 425984 + 64*16*4096
#define FLAG_BYTES 8192

__device__ __forceinline__ float sig_(float z)  { return __builtin_amdgcn_rcpf(1.f + __expf(-z)); }
__device__ __forceinline__ float tanh_(float z) { return 1.f - 2.f * __builtin_amdgcn_rcpf(1.f + __expf(2.f * z)); }

// Build fp16 MFMA B-fragment arrays.
// Frag index: ((wv*4+gi)*4+ks)*64 + lane ; lane holds W[gi*128+wv*16+(l&15)][ks*32+(l>>4)*8 + j]
__global__ __launch_bounds__(256) void prep_weights(
    const float* __restrict__ w_ih0, const float* __restrict__ w_hh0,
    const float* __restrict__ w_ih1, const float* __restrict__ w_hh1,
    _Float16* __restrict__ wf)
{
    const int idx = blockIdx.x * 256 + threadIdx.x;   // 0..8191
    const int l  = idx & 63;
    const int ks = (idx >> 6) & 3;
    const int gi = (idx >> 8) & 3;
    const int wv = (idx >> 10) & 7;
    const int row = gi * 128 + wv * 16 + (l & 15);
    const int kb  = ks * 32 + (l >> 4) * 8;
#pragma unroll
    for (int j = 0; j < 8; ++j) {
        wf[WHH0_H + idx * 8 + j] = (_Float16)w_hh0[row * 128 + kb + j];
        wf[WIH1_H + idx * 8 + j] = (_Float16)w_ih1[row * 128 + kb + j];
        wf[WHH1_H + idx * 8 + j] = (_Float16)w_hh1[row * 128 + kb + j];
    }
    if (ks == 0) {
        // x-frag convention: lk=0 -> W[0..7]; lk=1 -> 0,0,W[8..13]; lk>=2 -> 0
        const int lk = l >> 4;
        const int oi = ((wv * 4 + gi) * 64 + l) * 8;
#pragma unroll
        for (int j = 0; j < 8; ++j) {
            float v = 0.f;
            if (lk == 0)                v = w_ih0[row * 14 + j];
            else if (lk == 1 && j >= 2) v = w_ih0[row * 14 + 6 + j];
            wf[WIH0_H + oi + j] = (_Float16)v;
        }
    }
}

#define PIN(V) asm volatile("" : "+v"(V))

// read A-frags of h (XOR-swizzled LDS tile [batch][128 units])
#define READFRAG(DSTARR, SRC) do {                                              \
    _Pragma("unroll")                                                           \
    for (int ks = 0; ks < 4; ++ks) {                                            \
        const int off = lrow * 256 + ((ks * 64 + lk * 16) ^ ((lrow & 7) << 4)); \
        DSTARR[ks] = *(const half8*)((const char*)(SRC) + off);                 \
    }                                                                           \
} while (0)

__global__ __launch_bounds__(NTH, 2) void lstm2_pipe2(
    const float* __restrict__ x, const _Float16* __restrict__ wf,
    const float* __restrict__ b_ih0, const float* __restrict__ b_hh0,
    const float* __restrict__ b_ih1, const float* __restrict__ b_hh1,
    const float* __restrict__ w_lin, const float* __restrict__ b_lin,
    float* __restrict__ out, char* __restrict__ wsb)
{
    __shared__ __align__(16) _Float16 hs[2][BB * 128];   // own-layer h history, 2 x 4 KB

    const int tid  = threadIdx.x;
    const int l    = tid & 63;
    const int wv   = tid >> 6;
    const int lrow = l & 15;      // A row = batch ; D col = unit
    const int lk   = l >> 4;
    const int g    = blockIdx.x & 63;
    const int role = blockIdx.x >> 6;     // 0 = layer1 producer, 1 = layer2 consumer
    const int b0   = g * BB;
    const int u    = wv * 16 + lrow;      // this lane's unit (D col)

    _Float16* ring = (_Float16*)wsb + RING_H + (size_t)g * RING_W * 2048;
    int* fp = (int*)(wsb + FLAG_B) + g * 32;        // producer progress
    int* fc = fp + 16;                              // consumer progress (64 B apart)

    for (int i = tid; i < 2048; i += NTH) ((unsigned*)hs)[i] = 0u;

    const half8* wsf = (const half8*)wf;

    if (role == 0) {
        // ================= producer: layer 1 =================
        half8 whh0f[16], wih0f[4];
#pragma unroll
        for (int gi = 0; gi < 4; ++gi) {
#pragma unroll
            for (int ks = 0; ks < 4; ++ks) {
                whh0f[gi * 4 + ks] = wsf[WHH0_H / 8 + ((wv * 4 + gi) * 4 + ks) * 64 + l];
                PIN(whh0f[gi * 4 + ks]);
            }
            wih0f[gi] = wsf[WIH0_H / 8 + (wv * 4 + gi) * 64 + l];
            PIN(wih0f[gi]);
        }
        float bias1[4];
#pragma unroll
        for (int gi = 0; gi < 4; ++gi) {
            const int col = gi * 128 + wv * 16 + lrow;
            bias1[gi] = b_ih0[col] + b_hh0[col];
        }
        float c1[4] = {0.f, 0.f, 0.f, 0.f};
        const int coff = (lk == 1) ? 6 : 0;
        const float* xp = x + (size_t)(b0 + lrow) * (T_STEPS * 14) + coff;
        float xr[8];
#pragma unroll
        for (int j = 0; j < 8; ++j) xr[j] = xp[j];
        int seen_c = 0;
        __syncthreads();

        for (int t = 0; t < T_STEPS; ++t) {
            const int cur = t & 1, prv = cur ^ 1;
            half8 xh;
#pragma unroll
            for (int j = 0; j < 8; ++j) xh[j] = (_Float16)xr[j];

            half8 h1p[4];
            READFRAG(h1p, hs[prv]);

            floatx4 acc[4];
#pragma unroll
            for (int gi = 0; gi < 4; ++gi) {
                acc[gi] = (floatx4){bias1[gi], bias1[gi], bias1[gi], bias1[gi]};
                acc[gi] = __builtin_amdgcn_mfma_f32_16x16x32_f16(xh, wih0f[gi], acc[gi], 0, 0, 0);
#pragma unroll
                for (int ks = 0; ks < 4; ++ks)
                    acc[gi] = __builtin_amdgcn_mfma_f32_16x16x32_f16(h1p[ks], whh0f[gi * 4 + ks], acc[gi], 0, 0, 0);
            }

            // ring credit: slot t&15 must have been consumed (consumer done step t-15)
            if (t >= RING_W) {
                while (seen_c < t - (RING_W - 1)) {
                    seen_c = __hip_atomic_load(fc, __ATOMIC_RELAXED, __HIP_MEMORY_SCOPE_AGENT);
                    if (seen_c < t - (RING_W - 1)) __builtin_amdgcn_s_sleep(2);
                }
            }

            // activations -> LDS history + ring publish ([batch][unit] tile)
            {
                char* hwr = (char*)hs[cur];
                _Float16* rt = ring + (size_t)(t & (RING_W - 1)) * 2048;
#pragma unroll
                for (int r = 0; r < 4; ++r) {
                    const float ig = sig_(acc[0][r]);
                    const float fg = sig_(acc[1][r]);
                    const float gg = tanh_(acc[2][r]);
                    const float og = sig_(acc[3][r]);
                    c1[r] = fg * c1[r] + ig * gg;
                    const float hv = og * tanh_(c1[r]);
                    const int b = lk * 4 + r;
                    const _Float16 hh = (_Float16)hv;
                    *(_Float16*)(hwr + b * 256 + ((u * 2) ^ ((b & 7) << 4))) = hh;
                    rt[b * 128 + u] = hh;
                }
            }

            asm volatile("s_waitcnt vmcnt(0) lgkmcnt(0)" ::: "memory");
            __builtin_amdgcn_s_barrier();          // all waves' ring stores in L2
            if (tid == 0)
                __hip_atomic_store(fp, t + 1, __ATOMIC_RELEASE, __HIP_MEMORY_SCOPE_AGENT);
            if (t + 1 < T_STEPS) {
#pragma unroll
                for (int j = 0; j < 8; ++j) xr[j] = xp[(t + 1) * 14 + j];
            }
        }
    } else {
        // ================= consumer: layer 2 =================
        half8 wih1f[16], whh1f[16];
#pragma unroll
        for (int gi = 0; gi < 4; ++gi)
#pragma unroll
            for (int ks = 0; ks < 4; ++ks) {
                const int idx = ((wv * 4 + gi) * 4 + ks) * 64 + l;
                wih1f[gi * 4 + ks] = wsf[WIH1_H / 8 + idx];
                PIN(wih1f[gi * 4 + ks]);
                whh1f[gi * 4 + ks] = wsf[WHH1_H / 8 + idx];
                PIN(whh1f[gi * 4 + ks]);
            }
        float bias2[4];
#pragma unroll
        for (int gi = 0; gi < 4; ++gi) {
            const int col = gi * 128 + wv * 16 + lrow;
            bias2[gi] = b_ih1[col] + b_hh1[col];
        }
        float c2[4] = {0.f, 0.f, 0.f, 0.f};
        int seen_p = 0;
        const int toff = lrow * 256 + lk * 16;   // byte offset of A-frag ks=0 within ring tile

        __syncthreads();

#define WAITP(N) do {                                                               \
        while (seen_p < (N)) {                                                      \
            seen_p = __hip_atomic_load(fp, __ATOMIC_ACQUIRE, __HIP_MEMORY_SCOPE_AGENT); \
            if (seen_p < (N)) __builtin_amdgcn_s_sleep(2);                          \
        }                                                                           \
    } while (0)

        half8 h1nA[4], h1nB[4];
        WAITP(1);
#pragma unroll
        for (int ks = 0; ks < 4; ++ks)
            h1nA[ks] = *(const half8*)((const char*)ring + toff + ks * 64);
        WAITP(2);
#pragma unroll
        for (int ks = 0; ks < 4; ++ks)
            h1nB[ks] = *(const half8*)((const char*)ring + 4096 + toff + ks * 64);

#define CSTEP(T, H1N, CUR)                                                          \
        {                                                                           \
            half8 h2p[4];                                                           \
            READFRAG(h2p, hs[(CUR) ^ 1]);                                           \
            floatx4 acc[4];                                                         \
            _Pragma("unroll")                                                       \
            for (int gi = 0; gi < 4; ++gi) {                                        \
                acc[gi] = (floatx4){bias2[gi], bias2[gi], bias2[gi], bias2[gi]};    \
                _Pragma("unroll")                                                   \
                for (int ks = 0; ks < 4; ++ks) {                                    \
                    acc[gi] = __builtin_amdgcn_mfma_f32_16x16x32_f16(h2p[ks], whh1f[gi * 4 + ks], acc[gi], 0, 0, 0); \
                    acc[gi] = __builtin_amdgcn_mfma_f32_16x16x32_f16(H1N[ks], wih1f[gi * 4 + ks], acc[gi], 0, 0, 0); \
                }                                                                   \
            }                                                                       \
            char* hwr = (char*)hs[CUR];                                             \
            _Pragma("unroll")                                                       \
            for (int r = 0; r < 4; ++r) {                                           \
                const float ig = sig_(acc[0][r]);                                   \
                const float fg = sig_(acc[1][r]);                                   \
                const float gg = tanh_(acc[2][r]);                                  \
                const float og = sig_(acc[3][r]);                                   \
                c2[r] = fg * c2[r] + ig * gg;                                       \
                const float hv = og * tanh_(c2[r]);                                 \
                const int b = lk * 4 + r;                                           \
                *(_Float16*)(hwr + b * 256 + ((u * 2) ^ ((b & 7) << 4))) = (_Float16)hv; \
            }                                                                       \
            asm volatile("s_waitcnt lgkmcnt(0)" ::: "memory");                      \
            __builtin_amdgcn_s_barrier();                                           \
            if (tid == 0)                                                           \
                __hip_atomic_store(fc, (T) + 1, __ATOMIC_RELAXED, __HIP_MEMORY_SCOPE_AGENT); \
            if ((T) < T_STEPS - 2) {                                                \
                WAITP((T) + 3);                                                     \
                const char* rt = (const char*)ring + (size_t)(((T) + 2) & (RING_W - 1)) * 4096; \
                _Pragma("unroll")                                                   \
                for (int ks = 0; ks < 4; ++ks)                                      \
                    H1N[ks] = *(const half8*)(rt + toff + ks * 64);                 \
            }                                                                       \
        }

        for (int t = 0; t < T_STEPS; t += 2) {
            CSTEP(t,     h1nA, 0);
            CSTEP(t + 1, h1nB, 1);
        }
#undef CSTEP
#undef WAITP

        // epilogue: out[b] = h2(255)[b] . w_lin + b_lin ; h2(255) in hs[1]
        if (tid < 64) {
            const char* hb = (const char*)hs[1];
            const int bb = tid & 15, q = tid >> 4;
            float acc = 0.f;
#pragma unroll
            for (int j5 = 0; j5 < 32; ++j5) {
                const int j = q * 32 + j5;
                acc += w_lin[j] * (float)(*(const _Float16*)(hb + bb * 256 + ((j * 2) ^ ((bb & 7) << 4))));
            }
            acc += __shfl_xor(acc, 16, 64);
            acc += __shfl_xor(acc, 32, 64);
            if (q == 0) out[b0 + bb] = acc + b_lin[0];
        }
    }
}

extern "C" void kernel_launch(void* const* d_in, const int* in_sizes, int n_in,
                              void* d_out, int out_size, void* d_ws, size_t ws_size,
                              hipStream_t stream) {
    (void)in_sizes; (void)n_in; (void)ws_size; (void)out_size;
    const float* x     = (const float*)d_in[0];
    const float* w_ih0 = (const float*)d_in[1];
    const float* w_hh0 = (const float*)d_in[2];
    const float* b_ih0 = (const float*)d_in[3];
    const float* b_hh0 = (const float*)d_in[4];
    const float* w_ih1 = (const float*)d_in[5];
    const float* w_hh1 = (const float*)d_in[6];
    const float* b_ih1 = (const float*)d_in[7];
    const float* b_hh1 = (const float*)d_in[8];
    const float* w_lin = (const float*)d_in[9];
    const float* b_lin = (const float*)d_in[10];
    float* out = (float*)d_out;
    char* wsb = (char*)d_ws;

    hipMemsetAsync(wsb + FLAG_B, 0, FLAG_BYTES, stream);
    hipLaunchKernelGGL(prep_weights, dim3(32), dim3(256), 0, stream,
                       w_ih0, w_hh0, w_ih1, w_hh1, (_Float16*)d_ws);
    hipLaunchKernelGGL(lstm2_pipe2, dim3(128), dim3(NTH), 0, stream,
                       x, (const _Float16*)d_ws, b_ih0, b_hh0, b_ih1, b_hh1,
                       w_lin, b_lin, out, wsb);
}